// Round 8
// baseline (296.219 us; speedup 1.0000x reference)
//
#include <hip/hip_runtime.h>
#include <hip/hip_cooperative_groups.h>

namespace cg = cooperative_groups;

#define ALPHA 0.2f
constexpr int B_   = 64;
constexpr int N_   = 2048;
constexpr int IN_  = 1024;
constexpr int OUT_ = 1024;
constexpr int CHUNK = 256;            // rows per block in main phase (R4/R7-proven)
constexpr int NCH   = N_ / CHUNK;     // 8 chunks per batch
constexpr int RPW   = CHUNK / 4;      // 64 rows per wave (4 waves/block)
constexpr int GRID  = 512;            // 2 blocks/CU, exactly co-resident

// ---- workspace layout (float offsets), ~2.4 MB total ----
constexpr size_t WA2   = 0;        // 1024   : W^T a2
constexpr size_t E0P   = 1024;     // 64*64  : e0 partials [slab][b]
constexpr size_t ZPART = 5120;     // 512    : B*NCH
constexpr size_t GPART = 8192;     // B*NCH*IN = 524288
constexpr size_t GV    = 532480;   // B*IN = 65536

__device__ inline float wave_reduce_sum(float v) {
    #pragma unroll
    for (int off = 32; off > 0; off >>= 1) v += __shfl_xor(v, off);
    return v;
}

// One cooperative kernel, 4 phases separated by grid.sync().
// Phase bodies identical to the R7 kernels (kPre / kMain / kE / kF).
__global__ void __launch_bounds__(256, 2)
kAll(const float* __restrict__ W, const float* __restrict__ f,
     const float* __restrict__ wb, const float* __restrict__ aw,
     const float* __restrict__ ab, const float* __restrict__ bias,
     float* __restrict__ out, float* __restrict__ ws) {
    cg::grid_group grid = cg::this_grid();
    const int bid = blockIdx.x;
    const int t = threadIdx.x;
    const int wave = t >> 6, lane = t & 63;

    __shared__ float4 gbuf[4][256];     // main-phase reduce (16 KB)
    __shared__ float  zbuf[4];
    __shared__ float  s1[16][16], s2[16][16];
    __shared__ float  wa1L[16];
    __shared__ float  wbshare_s;
    __shared__ float  cstS;
    __shared__ float  zinv;

    // ---------- phase 0: prologue (blocks 0..63; slab s = bid) ----------
    if (bid < 64) {
        int s = bid;
        int c  = t & 15;             // col within slab
        int rg = t >> 4;             // 16 row-groups of 64 rows
        int col = s * 16 + c;
        float a1acc = 0.f, a2acc = 0.f;
        for (int i = 0; i < 64; ++i) {
            int d = rg * 64 + i;
            float w = W[(size_t)d * IN_ + col];
            a1acc += aw[d] * w;
            a2acc += aw[OUT_ + d] * w;
        }
        s1[rg][c] = a1acc;
        s2[rg][c] = a2acc;
        __syncthreads();
        if (t < 16) {
            float x1 = 0.f, x2 = 0.f;
            #pragma unroll
            for (int r = 0; r < 16; ++r) { x1 += s1[r][t]; x2 += s2[r][t]; }
            wa1L[t] = x1;
            ws[WA2 + s * 16 + t] = x2;
        }
        if (t == 0) {
            float x = 0.f;
            #pragma unroll
            for (int c2 = 0; c2 < 16; ++c2) {
                int cc = s * 16 + c2;
                x += wb[cc] * (aw[cc] + aw[OUT_ + cc]);
            }
            wbshare_s = x;
        }
        __syncthreads();
        int b = t >> 2, q = t & 3;   // 4 lanes per b, within-wave groups
        float4 fv = ((const float4*)(f + (size_t)b * N_ * IN_ + s * 16))[q];
        float4 w1 = ((const float4*)wa1L)[q];
        float dotv = fv.x * w1.x + fv.y * w1.y + fv.z * w1.z + fv.w * w1.w;
        dotv += __shfl_xor(dotv, 1);
        dotv += __shfl_xor(dotv, 2);
        if (q == 0) ws[E0P + s * 64 + b] = dotv + wbshare_s;
    }
    grid.sync();

    // ---------- phase 1: main feature pass (all 512 blocks) ----------
    {
        int b = bid >> 3, chunk = bid & 7;

        if (t < 64) {
            float v = ws[E0P + (size_t)t * 64 + b];
            v = wave_reduce_sum(v);
            if (t == 0) cstS = v + ab[0];
        }
        __syncthreads();
        float cst = cstS;

        const float4* wa2_4 = (const float4*)(ws + WA2);
        float4 ra2[4];
        #pragma unroll
        for (int k = 0; k < 4; ++k) ra2[k] = wa2_4[k * 64 + lane];

        const float4* fbase = (const float4*)(f + ((size_t)b * N_ + (size_t)chunk * CHUNK) * IN_);
        float4 acc[4];
        #pragma unroll
        for (int k = 0; k < 4; ++k) acc[k] = make_float4(0.f, 0.f, 0.f, 0.f);
        float z = 0.f;

        float4 v[4], nv[4];
        int r = wave;
        #pragma unroll
        for (int k = 0; k < 4; ++k) v[k] = fbase[(size_t)r * 256 + k * 64 + lane];

        for (int i = 0; i < RPW; ++i) {
            int rn = r + 4;
            if (i + 1 < RPW) {
                #pragma unroll
                for (int k = 0; k < 4; ++k) nv[k] = fbase[(size_t)rn * 256 + k * 64 + lane];
            }
            float dot = 0.f;
            #pragma unroll
            for (int k = 0; k < 4; ++k)
                dot += v[k].x * ra2[k].x + v[k].y * ra2[k].y + v[k].z * ra2[k].z + v[k].w * ra2[k].w;
            dot = wave_reduce_sum(dot);
            float e = dot + cst;
            e = e >= 0.f ? e : ALPHA * e;
            float w = __expf(e);
            z += w;
            #pragma unroll
            for (int k = 0; k < 4; ++k) {
                acc[k].x += w * v[k].x; acc[k].y += w * v[k].y;
                acc[k].z += w * v[k].z; acc[k].w += w * v[k].w;
            }
            if (i + 1 < RPW) {
                #pragma unroll
                for (int k = 0; k < 4; ++k) v[k] = nv[k];
            }
            r = rn;
        }

        #pragma unroll
        for (int k = 0; k < 4; ++k) gbuf[wave][k * 64 + lane] = acc[k];
        if (lane == 0) zbuf[wave] = z;
        __syncthreads();
        float4 p0 = gbuf[0][t], p1 = gbuf[1][t], p2 = gbuf[2][t], p3 = gbuf[3][t];
        float4 s = make_float4(p0.x + p1.x + p2.x + p3.x, p0.y + p1.y + p2.y + p3.y,
                               p0.z + p1.z + p2.z + p3.z, p0.w + p1.w + p2.w + p3.w);
        ((float4*)(ws + GPART))[((size_t)b * NCH + chunk) * 256 + t] = s;
        if (t == 0) ws[ZPART + b * NCH + chunk] = zbuf[0] + zbuf[1] + zbuf[2] + zbuf[3];
    }
    grid.sync();

    // ---------- phase 2: combine chunks, normalize (blocks 0..63) ----------
    if (bid < 64) {
        int b = bid;
        if (t == 0) {
            float zz = 0.f;
            #pragma unroll
            for (int c = 0; c < NCH; ++c) zz += ws[ZPART + b * NCH + c];
            zinv = 1.0f / zz;
        }
        __syncthreads();
        const float4* gp = (const float4*)(ws + GPART);
        float4 acc = make_float4(0.f, 0.f, 0.f, 0.f);
        #pragma unroll
        for (int c = 0; c < NCH; ++c) {
            float4 v = gp[((size_t)b * NCH + c) * 256 + t];
            acc.x += v.x; acc.y += v.y; acc.z += v.z; acc.w += v.w;
        }
        acc.x *= zinv; acc.y *= zinv; acc.z *= zinv; acc.w *= zinv;
        ((float4*)(ws + GV))[b * 256 + t] = acc;
    }
    grid.sync();

    // ---------- phase 3: output GEMV (all 512 blocks) ----------
    {
        int d  = (bid & 255) * 4 + wave;
        int b0 = (bid >> 8) * 32;
        const float4* w4 = (const float4*)(W + (size_t)d * IN_);
        float4 wreg[4];
        #pragma unroll
        for (int k = 0; k < 4; ++k) wreg[k] = w4[k * 64 + lane];
        float wbb = wb[d] + bias[d];
        const float4* gv = (const float4*)(ws + GV);
        #pragma unroll 4
        for (int bi = 0; bi < 32; ++bi) {
            int b = b0 + bi;
            float acc = 0.f;
            #pragma unroll
            for (int k = 0; k < 4; ++k) {
                float4 g = gv[b * 256 + k * 64 + lane];
                acc += g.x * wreg[k].x + g.y * wreg[k].y + g.z * wreg[k].z + g.w * wreg[k].w;
            }
            acc = wave_reduce_sum(acc);
            if (lane == 0) {
                float p = acc + wbb;
                out[(size_t)b * OUT_ + d] = p > 0.f ? p : 0.f;
            }
        }
    }
}

extern "C" void kernel_launch(void* const* d_in, const int* in_sizes, int n_in,
                              void* d_out, int out_size, void* d_ws, size_t ws_size,
                              hipStream_t stream) {
    const float* f    = (const float*)d_in[0];  // (64,2048,1024)
    const float* W    = (const float*)d_in[1];  // (1024,1024)
    const float* wb   = (const float*)d_in[2];  // (1024,)
    const float* aw   = (const float*)d_in[3];  // (2048,)
    const float* ab   = (const float*)d_in[4];  // scalar
    const float* bias = (const float*)d_in[5];  // (1024,)
    float* out = (float*)d_out;                 // (64,1,1024) f32
    float* ws  = (float*)d_ws;

    void* args[] = { (void*)&W, (void*)&f, (void*)&wb, (void*)&aw,
                     (void*)&ab, (void*)&bias, (void*)&out, (void*)&ws };
    hipLaunchCooperativeKernel((const void*)kAll, dim3(GRID), dim3(256),
                               args, 0, stream);
}

// Round 9
// 210.657 us; speedup vs baseline: 1.4062x; 1.4062x over previous
//
#include <hip/hip_runtime.h>

#define ALPHA 0.2f
constexpr int B_   = 64;
constexpr int N_   = 2048;
constexpr int IN_  = 1024;
constexpr int OUT_ = 1024;
constexpr int CHUNK = 256;            // rows per block in main pass (proven)
constexpr int NCH   = N_ / CHUNK;     // 8 chunks per batch
constexpr int RPW   = CHUNK / 4;      // 64 rows per wave (4 waves/block)

// ---- workspace layout (float offsets), ~2.4 MB total ----
constexpr size_t WA2   = 0;        // 1024   : W^T a2
constexpr size_t E0P   = 1024;     // 64*64  : e0 partials [slab][b]
constexpr size_t ZPART = 5120;     // 512    : B*NCH
constexpr size_t TICK  = 5632;     // 64 ints: per-b combine tickets
constexpr size_t GPART = 8192;     // B*NCH*IN = 524288
constexpr size_t GV    = 532480;   // B*IN = 65536

__device__ inline float wave_reduce_sum(float v) {
    #pragma unroll
    for (int off = 32; off > 0; off >>= 1) v += __shfl_xor(v, off);
    return v;
}

// Fused prologue (R7-proven). Block s owns cols [s*16, s*16+16):
//   wa2[cols], e0p[s][b]; also zeroes ticket[s].
__global__ void kPre(const float* __restrict__ W, const float* __restrict__ f,
                     const float* __restrict__ wb, const float* __restrict__ aw,
                     float* __restrict__ ws) {
    int s = blockIdx.x;          // 64 slabs
    int t = threadIdx.x;         // 256
    if (t == 0) ((int*)ws)[TICK + s] = 0;   // reset combine ticket for b=s
    int c  = t & 15;             // col within slab
    int rg = t >> 4;             // 16 row-groups of 64 rows
    int col = s * 16 + c;
    float a1acc = 0.f, a2acc = 0.f;
    for (int i = 0; i < 64; ++i) {
        int d = rg * 64 + i;
        float w = W[(size_t)d * IN_ + col];
        a1acc += aw[d] * w;
        a2acc += aw[OUT_ + d] * w;
    }
    __shared__ float s1[16][16], s2[16][16];
    __shared__ float wa1L[16];
    __shared__ float wbshare_s;
    s1[rg][c] = a1acc;
    s2[rg][c] = a2acc;
    __syncthreads();
    if (t < 16) {
        float x1 = 0.f, x2 = 0.f;
        #pragma unroll
        for (int r = 0; r < 16; ++r) { x1 += s1[r][t]; x2 += s2[r][t]; }
        wa1L[t] = x1;
        ws[WA2 + s * 16 + t] = x2;
    }
    if (t == 0) {
        float x = 0.f;
        #pragma unroll
        for (int c2 = 0; c2 < 16; ++c2) {
            int cc = s * 16 + c2;
            x += wb[cc] * (aw[cc] + aw[OUT_ + cc]);
        }
        wbshare_s = x;
    }
    __syncthreads();
    int b = t >> 2, q = t & 3;   // 4 lanes per b
    float4 fv = ((const float4*)(f + (size_t)b * N_ * IN_ + s * 16))[q];
    float4 w1 = ((const float4*)wa1L)[q];
    float dotv = fv.x * w1.x + fv.y * w1.y + fv.z * w1.z + fv.w * w1.w;
    dotv += __shfl_xor(dotv, 1);
    dotv += __shfl_xor(dotv, 2);
    if (q == 0) ws[E0P + s * 64 + b] = dotv + wbshare_s;
}

// Main feature pass (R7-proven body) + fused per-b combine epilogue:
// the last of the 8 chunk-blocks for batch b (ticket==7) sums GPART/ZPART
// and writes GV[b,:] = (sum_c gpart)/z.  Fixed-order sum -> deterministic.
__global__ void kMain(const float* __restrict__ f, const float* __restrict__ ab,
                      float* __restrict__ ws) {
    int b = blockIdx.y, chunk = blockIdx.x;
    int t = threadIdx.x, wave = t >> 6, lane = t & 63;

    __shared__ float cstS;
    if (t < 64) {
        float v = ws[E0P + (size_t)t * 64 + b];
        v = wave_reduce_sum(v);
        if (t == 0) cstS = v + ab[0];
    }
    __syncthreads();
    float cst = cstS;

    const float4* wa2_4 = (const float4*)(ws + WA2);
    float4 ra2[4];
    #pragma unroll
    for (int k = 0; k < 4; ++k) ra2[k] = wa2_4[k * 64 + lane];

    const float4* fbase = (const float4*)(f + ((size_t)b * N_ + (size_t)chunk * CHUNK) * IN_);
    float4 acc[4];
    #pragma unroll
    for (int k = 0; k < 4; ++k) acc[k] = make_float4(0.f, 0.f, 0.f, 0.f);
    float z = 0.f;

    float4 v[4], nv[4];
    int r = wave;
    #pragma unroll
    for (int k = 0; k < 4; ++k) v[k] = fbase[(size_t)r * 256 + k * 64 + lane];

    for (int i = 0; i < RPW; ++i) {
        int rn = r + 4;
        if (i + 1 < RPW) {
            #pragma unroll
            for (int k = 0; k < 4; ++k) nv[k] = fbase[(size_t)rn * 256 + k * 64 + lane];
        }
        float dot = 0.f;
        #pragma unroll
        for (int k = 0; k < 4; ++k)
            dot += v[k].x * ra2[k].x + v[k].y * ra2[k].y + v[k].z * ra2[k].z + v[k].w * ra2[k].w;
        dot = wave_reduce_sum(dot);
        float e = dot + cst;
        e = e >= 0.f ? e : ALPHA * e;
        float w = __expf(e);
        z += w;
        #pragma unroll
        for (int k = 0; k < 4; ++k) {
            acc[k].x += w * v[k].x; acc[k].y += w * v[k].y;
            acc[k].z += w * v[k].z; acc[k].w += w * v[k].w;
        }
        if (i + 1 < RPW) {
            #pragma unroll
            for (int k = 0; k < 4; ++k) v[k] = nv[k];
        }
        r = rn;
    }

    __shared__ float4 gbuf[4][256];
    __shared__ float  zbuf[4];
    #pragma unroll
    for (int k = 0; k < 4; ++k) gbuf[wave][k * 64 + lane] = acc[k];
    if (lane == 0) zbuf[wave] = z;
    __syncthreads();
    float4 p0 = gbuf[0][t], p1 = gbuf[1][t], p2 = gbuf[2][t], p3 = gbuf[3][t];
    float4 s = make_float4(p0.x + p1.x + p2.x + p3.x, p0.y + p1.y + p2.y + p3.y,
                           p0.z + p1.z + p2.z + p3.z, p0.w + p1.w + p2.w + p3.w);
    ((float4*)(ws + GPART))[((size_t)b * NCH + chunk) * 256 + t] = s;
    if (t == 0) ws[ZPART + b * NCH + chunk] = zbuf[0] + zbuf[1] + zbuf[2] + zbuf[3];

    // ---- fused combine: last chunk-block of this b does kE's job ----
    __threadfence();                       // release GPART/ZPART device-wide
    __shared__ int tkt;
    if (t == 0) tkt = atomicAdd((int*)ws + TICK + b, 1);
    __syncthreads();
    if (tkt == NCH - 1) {
        __threadfence();                   // acquire other blocks' writes
        float zz = 0.f;
        #pragma unroll
        for (int c = 0; c < NCH; ++c) zz += ws[ZPART + b * NCH + c];
        float zi = 1.0f / zz;
        const float4* gp = (const float4*)(ws + GPART);
        float4 a = gp[((size_t)b * NCH) * 256 + t];
        #pragma unroll
        for (int c = 1; c < NCH; ++c) {
            float4 u = gp[((size_t)b * NCH + c) * 256 + t];
            a.x += u.x; a.y += u.y; a.z += u.z; a.w += u.w;
        }
        a.x *= zi; a.y *= zi; a.z *= zi; a.w *= zi;
        ((float4*)(ws + GV))[b * 256 + t] = a;
    }
}

// out[b,d] = relu( g[b,:].W[d,:] + w_b[d] + bias_out[d] )
// grid(256,2): block = (4 d's, 32 b's). W rows in registers; g from L2.
__global__ void kF(const float* __restrict__ W, const float* __restrict__ wb,
                   const float* __restrict__ bias, const float* __restrict__ ws,
                   float* __restrict__ out) {
    int t = threadIdx.x, wave = t >> 6, lane = t & 63;
    int d  = blockIdx.x * 4 + wave;
    int b0 = blockIdx.y * 32;
    const float4* w4 = (const float4*)(W + (size_t)d * IN_);
    float4 wreg[4];
    #pragma unroll
    for (int k = 0; k < 4; ++k) wreg[k] = w4[k * 64 + lane];
    float wbb = wb[d] + bias[d];
    const float4* gv = (const float4*)(ws + GV);
    #pragma unroll 4
    for (int bi = 0; bi < 32; ++bi) {
        int b = b0 + bi;
        float acc = 0.f;
        #pragma unroll
        for (int k = 0; k < 4; ++k) {
            float4 g = gv[b * 256 + k * 64 + lane];
            acc += g.x * wreg[k].x + g.y * wreg[k].y + g.z * wreg[k].z + g.w * wreg[k].w;
        }
        acc = wave_reduce_sum(acc);
        if (lane == 0) {
            float p = acc + wbb;
            out[(size_t)b * OUT_ + d] = p > 0.f ? p : 0.f;
        }
    }
}

extern "C" void kernel_launch(void* const* d_in, const int* in_sizes, int n_in,
                              void* d_out, int out_size, void* d_ws, size_t ws_size,
                              hipStream_t stream) {
    const float* f    = (const float*)d_in[0];  // (64,2048,1024)
    const float* W    = (const float*)d_in[1];  // (1024,1024)
    const float* wb   = (const float*)d_in[2];  // (1024,)
    const float* aw   = (const float*)d_in[3];  // (2048,)
    const float* ab   = (const float*)d_in[4];  // scalar
    const float* bias = (const float*)d_in[5];  // (1024,)
    float* out = (float*)d_out;                 // (64,1,1024) f32
    float* ws  = (float*)d_ws;

    kPre <<<dim3(64), 256, 0, stream>>>(W, f, wb, aw, ws);
    kMain<<<dim3(NCH, B_), 256, 0, stream>>>(f, ab, ws);
    kF   <<<dim3(OUT_ / 4, 2), 256, 0, stream>>>(W, wb, bias, ws, out);
}

// Round 10
// 139.380 us; speedup vs baseline: 2.1253x; 1.5114x over previous
//
#include <hip/hip_runtime.h>

#define ALPHA 0.2f
constexpr int B_   = 64;
constexpr int N_   = 2048;
constexpr int IN_  = 1024;
constexpr int OUT_ = 1024;
constexpr int CHUNK = 256;            // rows per block in main pass (proven)
constexpr int NCH   = N_ / CHUNK;     // 8 chunks per batch
constexpr int RPW   = CHUNK / 4;      // 64 rows per wave (4 waves/block)

// Fixed-point scales: integer sums are order-independent -> bitwise
// deterministic without device fences. Relative error ~2^-24.
#define SCALE_G 16777216.0f           // 2^24
#define SCALE_Z 1048576.0f            // 2^20

// ---- workspace layout (float offsets), ~557 KB total ----
constexpr size_t WA2   = 0;        // 1024    : W^T a2
constexpr size_t E0P   = 1024;     // 64*64   : e0 partials [slab][b]
constexpr size_t ZT    = 5120;     // 64 ll   : per-b z accumulator (int64 fx)
constexpr size_t GV64  = 8192;     // 64*1024 ll : per-b g accumulator (int64 fx)

__device__ inline float wave_reduce_sum(float v) {
    #pragma unroll
    for (int off = 32; off > 0; off >>= 1) v += __shfl_xor(v, off);
    return v;
}

// Fused prologue (R7-proven). Block s owns cols [s*16, s*16+16):
//   wa2[cols], e0p[s][b]; also zeroes GV64[s][:] and ZT[s].
__global__ void kPre(const float* __restrict__ W, const float* __restrict__ f,
                     const float* __restrict__ wb, const float* __restrict__ aw,
                     float* __restrict__ ws) {
    int s = blockIdx.x;          // 64 slabs
    int t = threadIdx.x;         // 256
    // zero this b's accumulators (stream-ordered before kMain's atomics)
    long long* gv = (long long*)(ws + GV64) + (size_t)s * 1024;
    #pragma unroll
    for (int i = 0; i < 4; ++i) gv[t + i * 256] = 0;
    if (t == 0) ((long long*)(ws + ZT))[s] = 0;

    int c  = t & 15;             // col within slab
    int rg = t >> 4;             // 16 row-groups of 64 rows
    int col = s * 16 + c;
    float a1acc = 0.f, a2acc = 0.f;
    for (int i = 0; i < 64; ++i) {
        int d = rg * 64 + i;
        float w = W[(size_t)d * IN_ + col];
        a1acc += aw[d] * w;
        a2acc += aw[OUT_ + d] * w;
    }
    __shared__ float s1[16][16], s2[16][16];
    __shared__ float wa1L[16];
    __shared__ float wbshare_s;
    s1[rg][c] = a1acc;
    s2[rg][c] = a2acc;
    __syncthreads();
    if (t < 16) {
        float x1 = 0.f, x2 = 0.f;
        #pragma unroll
        for (int r = 0; r < 16; ++r) { x1 += s1[r][t]; x2 += s2[r][t]; }
        wa1L[t] = x1;
        ws[WA2 + s * 16 + t] = x2;
    }
    if (t == 0) {
        float x = 0.f;
        #pragma unroll
        for (int c2 = 0; c2 < 16; ++c2) {
            int cc = s * 16 + c2;
            x += wb[cc] * (aw[cc] + aw[OUT_ + cc]);
        }
        wbshare_s = x;
    }
    __syncthreads();
    int b = t >> 2, q = t & 3;   // 4 lanes per b
    float4 fv = ((const float4*)(f + (size_t)b * N_ * IN_ + s * 16))[q];
    float4 w1 = ((const float4*)wa1L)[q];
    float dotv = fv.x * w1.x + fv.y * w1.y + fv.z * w1.z + fv.w * w1.w;
    dotv += __shfl_xor(dotv, 1);
    dotv += __shfl_xor(dotv, 2);
    if (q == 0) ws[E0P + s * 64 + b] = dotv + wbshare_s;
}

// Main feature pass (R7-proven body); epilogue accumulates the block's
// g/z partials into int64 fixed-point via atomicAdd (order-independent,
// deterministic, no fences).
__global__ void kMain(const float* __restrict__ f, const float* __restrict__ ab,
                      float* __restrict__ ws) {
    int b = blockIdx.y, chunk = blockIdx.x;
    int t = threadIdx.x, wave = t >> 6, lane = t & 63;

    __shared__ float cstS;
    if (t < 64) {
        float v = ws[E0P + (size_t)t * 64 + b];
        v = wave_reduce_sum(v);
        if (t == 0) cstS = v + ab[0];
    }
    __syncthreads();
    float cst = cstS;

    const float4* wa2_4 = (const float4*)(ws + WA2);
    float4 ra2[4];
    #pragma unroll
    for (int k = 0; k < 4; ++k) ra2[k] = wa2_4[k * 64 + lane];

    const float4* fbase = (const float4*)(f + ((size_t)b * N_ + (size_t)chunk * CHUNK) * IN_);
    float4 acc[4];
    #pragma unroll
    for (int k = 0; k < 4; ++k) acc[k] = make_float4(0.f, 0.f, 0.f, 0.f);
    float z = 0.f;

    float4 v[4], nv[4];
    int r = wave;
    #pragma unroll
    for (int k = 0; k < 4; ++k) v[k] = fbase[(size_t)r * 256 + k * 64 + lane];

    for (int i = 0; i < RPW; ++i) {
        int rn = r + 4;
        if (i + 1 < RPW) {
            #pragma unroll
            for (int k = 0; k < 4; ++k) nv[k] = fbase[(size_t)rn * 256 + k * 64 + lane];
        }
        float dot = 0.f;
        #pragma unroll
        for (int k = 0; k < 4; ++k)
            dot += v[k].x * ra2[k].x + v[k].y * ra2[k].y + v[k].z * ra2[k].z + v[k].w * ra2[k].w;
        dot = wave_reduce_sum(dot);
        float e = dot + cst;
        e = e >= 0.f ? e : ALPHA * e;
        float w = __expf(e);
        z += w;
        #pragma unroll
        for (int k = 0; k < 4; ++k) {
            acc[k].x += w * v[k].x; acc[k].y += w * v[k].y;
            acc[k].z += w * v[k].z; acc[k].w += w * v[k].w;
        }
        if (i + 1 < RPW) {
            #pragma unroll
            for (int k = 0; k < 4; ++k) v[k] = nv[k];
        }
        r = rn;
    }

    __shared__ float4 gbuf[4][256];
    __shared__ float  zbuf[4];
    #pragma unroll
    for (int k = 0; k < 4; ++k) gbuf[wave][k * 64 + lane] = acc[k];
    if (lane == 0) zbuf[wave] = z;
    __syncthreads();
    float4 p0 = gbuf[0][t], p1 = gbuf[1][t], p2 = gbuf[2][t], p3 = gbuf[3][t];
    float4 s = make_float4(p0.x + p1.x + p2.x + p3.x, p0.y + p1.y + p2.y + p3.y,
                           p0.z + p1.z + p2.z + p3.z, p0.w + p1.w + p2.w + p3.w);

    unsigned long long* gv = (unsigned long long*)(ws + GV64) + (size_t)b * 1024 + (size_t)t * 4;
    atomicAdd(gv + 0, (unsigned long long)(long long)llrintf(s.x * SCALE_G));
    atomicAdd(gv + 1, (unsigned long long)(long long)llrintf(s.y * SCALE_G));
    atomicAdd(gv + 2, (unsigned long long)(long long)llrintf(s.z * SCALE_G));
    atomicAdd(gv + 3, (unsigned long long)(long long)llrintf(s.w * SCALE_G));
    if (t == 0) {
        float zz = zbuf[0] + zbuf[1] + zbuf[2] + zbuf[3];
        atomicAdd((unsigned long long*)(ws + ZT) + b,
                  (unsigned long long)(long long)llrintf(zz * SCALE_Z));
    }
}

// out[b,d] = relu( (g64[b,:]/2^24 / z) . W[d,:] + w_b[d] + bias_out[d] )
// grid(256,2): block = (4 d's, 32 b's). W rows in registers; g from L2.
__global__ void kF(const float* __restrict__ W, const float* __restrict__ wb,
                   const float* __restrict__ bias, const float* __restrict__ ws,
                   float* __restrict__ out) {
    int t = threadIdx.x, wave = t >> 6, lane = t & 63;
    int d  = blockIdx.x * 4 + wave;
    int b0 = blockIdx.y * 32;
    const float4* w4 = (const float4*)(W + (size_t)d * IN_);
    float4 wreg[4];
    #pragma unroll
    for (int k = 0; k < 4; ++k) wreg[k] = w4[k * 64 + lane];
    float wbb = wb[d] + bias[d];
    const long long* gv64 = (const long long*)(ws + GV64);
    const long long* zt   = (const long long*)(ws + ZT);
    for (int bi = 0; bi < 32; ++bi) {
        int b = b0 + bi;
        double si = (1.0 / ((double)zt[b] * (1.0 / (double)SCALE_Z)))
                  * (1.0 / (double)SCALE_G);
        const long long* gb = gv64 + (size_t)b * 1024;
        float acc = 0.f;
        #pragma unroll
        for (int k = 0; k < 4; ++k) {
            int i4 = (k * 64 + lane) * 4;
            float g0 = (float)((double)gb[i4 + 0] * si);
            float g1 = (float)((double)gb[i4 + 1] * si);
            float g2 = (float)((double)gb[i4 + 2] * si);
            float g3 = (float)((double)gb[i4 + 3] * si);
            acc += g0 * wreg[k].x + g1 * wreg[k].y + g2 * wreg[k].z + g3 * wreg[k].w;
        }
        acc = wave_reduce_sum(acc);
        if (lane == 0) {
            float p = acc + wbb;
            out[(size_t)b * OUT_ + d] = p > 0.f ? p : 0.f;
        }
    }
}

extern "C" void kernel_launch(void* const* d_in, const int* in_sizes, int n_in,
                              void* d_out, int out_size, void* d_ws, size_t ws_size,
                              hipStream_t stream) {
    const float* f    = (const float*)d_in[0];  // (64,2048,1024)
    const float* W    = (const float*)d_in[1];  // (1024,1024)
    const float* wb   = (const float*)d_in[2];  // (1024,)
    const float* aw   = (const float*)d_in[3];  // (2048,)
    const float* ab   = (const float*)d_in[4];  // scalar
    const float* bias = (const float*)d_in[5];  // (1024,)
    float* out = (float*)d_out;                 // (64,1,1024) f32
    float* ws  = (float*)d_ws;

    kPre <<<dim3(64), 256, 0, stream>>>(W, f, wb, aw, ws);
    kMain<<<dim3(NCH, B_), 256, 0, stream>>>(f, ab, ws);
    kF   <<<dim3(OUT_ / 4, 2), 256, 0, stream>>>(W, wb, bias, ws, out);
}

// Round 11
// 122.350 us; speedup vs baseline: 2.4211x; 1.1392x over previous
//
#include <hip/hip_runtime.h>

#define ALPHA 0.2f
constexpr int B_   = 64;
constexpr int N_   = 2048;
constexpr int IN_  = 1024;
constexpr int OUT_ = 1024;
constexpr int CHUNK = 256;            // rows per workgroup in main pass (R4-proven)
constexpr int NCH   = N_ / CHUNK;     // 8 chunks per batch
constexpr int RPW   = CHUNK / 4;      // 64 rows per wave (4 waves/block)

// ---- workspace layout (float offsets), ~2.4 MB total ----
// R7 structure (122.2 µs, best): kPre -> kMain -> kE -> kF.
// Proven-null alternatives (do not revisit): grid.sync fusion (R8, +174us),
// threadfence ticket-combine (R9, +88us), int64 atomic combine (R10, +17us),
// kMain occupancy/pipeline variants (R4/R5/R6, null => BW-bound).
constexpr size_t WA2   = 0;        // 1024   : W^T a2
constexpr size_t E0P   = 1024;     // 64*64  : e0 partials [slab][b]
constexpr size_t ZPART = 5120;     // 512    : B*NCH
constexpr size_t GPART = 8192;     // B*NCH*IN = 524288
constexpr size_t GV    = 532480;   // B*IN = 65536

__device__ inline float wave_reduce_sum(float v) {
    #pragma unroll
    for (int off = 32; off > 0; off >>= 1) v += __shfl_xor(v, off);
    return v;
}

// Fused prologue, no cross-block reduction. Block s owns cols [s*16, s*16+16):
//   wa2[cols] = sum_d W[d,col]*a2[d]
//   e0p[s][b] = sum_{col in slab} f[b,0,col]*wa1_local[col] + wb[col]*(a1+a2)[col]
// kMain sums e0p over s.
__global__ void kPre(const float* __restrict__ W, const float* __restrict__ f,
                     const float* __restrict__ wb, const float* __restrict__ aw,
                     float* __restrict__ ws) {
    int s = blockIdx.x;          // 64 slabs
    int t = threadIdx.x;         // 256
    int c  = t & 15;             // col within slab
    int rg = t >> 4;             // 16 row-groups of 64 rows
    int col = s * 16 + c;
    float a1acc = 0.f, a2acc = 0.f;
    for (int i = 0; i < 64; ++i) {
        int d = rg * 64 + i;
        float w = W[(size_t)d * IN_ + col];
        a1acc += aw[d] * w;
        a2acc += aw[OUT_ + d] * w;
    }
    __shared__ float s1[16][16], s2[16][16];
    __shared__ float wa1L[16];
    __shared__ float wbshare_s;
    s1[rg][c] = a1acc;
    s2[rg][c] = a2acc;
    __syncthreads();
    if (t < 16) {
        float x1 = 0.f, x2 = 0.f;
        #pragma unroll
        for (int r = 0; r < 16; ++r) { x1 += s1[r][t]; x2 += s2[r][t]; }
        wa1L[t] = x1;
        ws[WA2 + s * 16 + t] = x2;
    }
    if (t == 0) {
        float x = 0.f;
        #pragma unroll
        for (int c2 = 0; c2 < 16; ++c2) {
            int cc = s * 16 + c2;
            x += wb[cc] * (aw[cc] + aw[OUT_ + cc]);
        }
        wbshare_s = x;
    }
    __syncthreads();
    // e0 partials: thread -> (b = t>>2, q = t&3), 4 lanes per b
    int b = t >> 2, q = t & 3;
    float4 fv = ((const float4*)(f + (size_t)b * N_ * IN_ + s * 16))[q];
    float4 w1 = ((const float4*)wa1L)[q];
    float dotv = fv.x * w1.x + fv.y * w1.y + fv.z * w1.z + fv.w * w1.w;
    dotv += __shfl_xor(dotv, 1);
    dotv += __shfl_xor(dotv, 2);
    if (q == 0) ws[E0P + s * 64 + b] = dotv + wbshare_s;
}

// Single feature pass: per row n, s=f.wa2, w=exp(leaky(e0+s+ab)),
// accumulate gpart += w*f and zpart += w.   Wave-per-row, reg double-buffer.
// BW-bound at ~90% of copy ceiling (R4/R5/R6 occupancy/pipeline nulls).
__global__ void kMain(const float* __restrict__ f, const float* __restrict__ ab,
                      float* __restrict__ ws) {
    int b = blockIdx.y, chunk = blockIdx.x;
    int t = threadIdx.x, wave = t >> 6, lane = t & 63;

    __shared__ float cstS;
    if (t < 64) {
        float v = ws[E0P + (size_t)t * 64 + b];
        v = wave_reduce_sum(v);
        if (t == 0) cstS = v + ab[0];
    }
    __syncthreads();
    float cst = cstS;

    const float4* wa2_4 = (const float4*)(ws + WA2);
    float4 ra2[4];
    #pragma unroll
    for (int k = 0; k < 4; ++k) ra2[k] = wa2_4[k * 64 + lane];

    const float4* fbase = (const float4*)(f + ((size_t)b * N_ + (size_t)chunk * CHUNK) * IN_);
    float4 acc[4];
    #pragma unroll
    for (int k = 0; k < 4; ++k) acc[k] = make_float4(0.f, 0.f, 0.f, 0.f);
    float z = 0.f;

    float4 v[4], nv[4];
    int r = wave;
    #pragma unroll
    for (int k = 0; k < 4; ++k) v[k] = fbase[(size_t)r * 256 + k * 64 + lane];

    for (int i = 0; i < RPW; ++i) {
        int rn = r + 4;
        if (i + 1 < RPW) {
            #pragma unroll
            for (int k = 0; k < 4; ++k) nv[k] = fbase[(size_t)rn * 256 + k * 64 + lane];
        }
        float dot = 0.f;
        #pragma unroll
        for (int k = 0; k < 4; ++k)
            dot += v[k].x * ra2[k].x + v[k].y * ra2[k].y + v[k].z * ra2[k].z + v[k].w * ra2[k].w;
        dot = wave_reduce_sum(dot);
        float e = dot + cst;
        e = e >= 0.f ? e : ALPHA * e;
        float w = __expf(e);
        z += w;
        #pragma unroll
        for (int k = 0; k < 4; ++k) {
            acc[k].x += w * v[k].x; acc[k].y += w * v[k].y;
            acc[k].z += w * v[k].z; acc[k].w += w * v[k].w;
        }
        if (i + 1 < RPW) {
            #pragma unroll
            for (int k = 0; k < 4; ++k) v[k] = nv[k];
        }
        r = rn;
    }

    __shared__ float4 gbuf[4][256];
    __shared__ float  zbuf[4];
    #pragma unroll
    for (int k = 0; k < 4; ++k) gbuf[wave][k * 64 + lane] = acc[k];
    if (lane == 0) zbuf[wave] = z;
    __syncthreads();
    float4 s0 = gbuf[0][t], s1 = gbuf[1][t], s2 = gbuf[2][t], s3 = gbuf[3][t];
    float4 s = make_float4(s0.x + s1.x + s2.x + s3.x, s0.y + s1.y + s2.y + s3.y,
                           s0.z + s1.z + s2.z + s3.z, s0.w + s1.w + s2.w + s3.w);
    ((float4*)(ws + GPART))[((size_t)b * NCH + chunk) * 256 + t] = s;
    if (t == 0) ws[ZPART + b * NCH + chunk] = zbuf[0] + zbuf[1] + zbuf[2] + zbuf[3];
}

// g[b,:] = (sum_c gpart[b,c,:]) / (sum_c zpart[b,c])
__global__ void kE(float* __restrict__ ws) {
    int b = blockIdx.x, t = threadIdx.x;
    __shared__ float zinv;
    if (t == 0) {
        float zz = 0.f;
        #pragma unroll
        for (int c = 0; c < NCH; ++c) zz += ws[ZPART + b * NCH + c];
        zinv = 1.0f / zz;
    }
    __syncthreads();
    const float4* gp = (const float4*)(ws + GPART);
    float4 acc = make_float4(0.f, 0.f, 0.f, 0.f);
    #pragma unroll
    for (int c = 0; c < NCH; ++c) {
        float4 v = gp[((size_t)b * NCH + c) * 256 + t];
        acc.x += v.x; acc.y += v.y; acc.z += v.z; acc.w += v.w;
    }
    acc.x *= zinv; acc.y *= zinv; acc.z *= zinv; acc.w *= zinv;
    ((float4*)(ws + GV))[b * 256 + t] = acc;
}

// out[b,d] = relu( g[b,:].W[d,:] + w_b[d] + bias_out[d] )
// grid(256,2): block = (4 d's, 32 b's). W rows in registers; g from L2.
__global__ void kF(const float* __restrict__ W, const float* __restrict__ wb,
                   const float* __restrict__ bias, const float* __restrict__ ws,
                   float* __restrict__ out) {
    int t = threadIdx.x, wave = t >> 6, lane = t & 63;
    int d  = blockIdx.x * 4 + wave;
    int b0 = blockIdx.y * 32;
    const float4* w4 = (const float4*)(W + (size_t)d * IN_);
    float4 wreg[4];
    #pragma unroll
    for (int k = 0; k < 4; ++k) wreg[k] = w4[k * 64 + lane];
    float wbb = wb[d] + bias[d];
    const float4* gv = (const float4*)(ws + GV);
    #pragma unroll 4
    for (int bi = 0; bi < 32; ++bi) {
        int b = b0 + bi;
        float acc = 0.f;
        #pragma unroll
        for (int k = 0; k < 4; ++k) {
            float4 g = gv[b * 256 + k * 64 + lane];
            acc += g.x * wreg[k].x + g.y * wreg[k].y + g.z * wreg[k].z + g.w * wreg[k].w;
        }
        acc = wave_reduce_sum(acc);
        if (lane == 0) {
            float p = acc + wbb;
            out[(size_t)b * OUT_ + d] = p > 0.f ? p : 0.f;
        }
    }
}

extern "C" void kernel_launch(void* const* d_in, const int* in_sizes, int n_in,
                              void* d_out, int out_size, void* d_ws, size_t ws_size,
                              hipStream_t stream) {
    const float* f    = (const float*)d_in[0];  // (64,2048,1024)
    const float* W    = (const float*)d_in[1];  // (1024,1024)
    const float* wb   = (const float*)d_in[2];  // (1024,)
    const float* aw   = (const float*)d_in[3];  // (2048,)
    const float* ab   = (const float*)d_in[4];  // scalar
    const float* bias = (const float*)d_in[5];  // (1024,)
    float* out = (float*)d_out;                 // (64,1,1024) f32
    float* ws  = (float*)d_ws;

    kPre <<<dim3(64), 256, 0, stream>>>(W, f, wb, aw, ws);
    kMain<<<dim3(NCH, B_), 256, 0, stream>>>(f, ab, ws);
    kE   <<<dim3(B_), 256, 0, stream>>>(ws);
    kF   <<<dim3(OUT_ / 4, 2), 256, 0, stream>>>(W, wb, bias, ws, out);
}